// Round 9
// baseline (380.789 us; speedup 1.0000x reference)
//
#include <hip/hip_runtime.h>
#include <hip/hip_bf16.h>

#define SS 2048
#define DDIM 1024

typedef unsigned short u16;
typedef unsigned int u32;
typedef __attribute__((ext_vector_type(8))) short bf16x8_t;
typedef __attribute__((ext_vector_type(4))) float f32x4_t;

__device__ __forceinline__ u16 f2bf(float f) {
  __hip_bfloat16 h = __float2bfloat16(f);
  return *reinterpret_cast<u16*>(&h);
}

// async global->LDS, 16 B per lane. LDS dest = (wave-uniform) base + lane*16.
__device__ __forceinline__ void gld16(const void* g, void* lds_base) {
  __builtin_amdgcn_global_load_lds(
      (const __attribute__((address_space(1))) u32*)(uintptr_t)g,
      (__attribute__((address_space(3))) u32*)(u32)(uintptr_t)lds_base,
      16, 0, 0);
}

// ---------------------------------------------------------------------------
// Fused prep: zbuf zero + f32->bf16 converts + weight repacks. Grid 10240.
// ---------------------------------------------------------------------------
__global__ __launch_bounds__(256) void prep_kernel(
    const float* __restrict__ q, const float* __restrict__ k,
    const float* __restrict__ v, const float* __restrict__ wq_w,
    const float* __restrict__ wk_w, const float* __restrict__ wv_w,
    const float* __restrict__ wc_w, u16* __restrict__ Xq,
    u16* __restrict__ Xk, u16* __restrict__ Xv, u16* __restrict__ Wqr,
    u16* __restrict__ Wkr, u16* __restrict__ Wvr, u16* __restrict__ Wcr,
    u32* __restrict__ zbuf) {
  const int bid = blockIdx.x;
  const int tid = threadIdx.x;
  if (bid == 0 && tid < 64) zbuf[tid] = 0u;

  if (bid < 6144) {
    const int z = bid >> 11;            // 0..2
    const int bx = bid & 2047;
    const float* src = (z == 0) ? q : (z == 1) ? k : v;
    u16* dst = (z == 0) ? Xq : (z == 1) ? Xk : Xv;
    int i = bx * 256 + tid;
    const float4* s = (const float4*)src + (size_t)i * 2;
    float4 f0 = s[0], f1 = s[1];
    u16 o[8] = {f2bf(f0.x), f2bf(f0.y), f2bf(f0.z), f2bf(f0.w),
                f2bf(f1.x), f2bf(f1.y), f2bf(f1.z), f2bf(f1.w)};
    *(uint4*)(dst + (size_t)i * 8) = *(const uint4*)o;
  } else if (bid < 8192) {
    const int idx = bid - 6144;
    const float* w = (idx >= 1024) ? wk_w : wq_w;
    u16* out = (idx >= 1024) ? Wkr : Wqr;
    const int o = idx & 1023;
    for (int j = tid; j < 3072; j += 256) {
      int i = j / 3, t = j - i * 3;
      out[(size_t)o * 3072 + t * 1024 + i] = f2bf(w[(size_t)o * 3072 + j]);
    }
  } else {
    const int idx = bid - 8192;
    const float* w = (idx >= 1024) ? wc_w : wv_w;
    u16* out = (idx >= 1024) ? Wcr : Wvr;
    const int bx = idx & 1023;
    size_t i = (size_t)bx * 1024 + tid * 4;
    float4 f = *(const float4*)(w + i);
    u16 o4[4] = {f2bf(f.x), f2bf(f.y), f2bf(f.z), f2bf(f.w)};
    *(ushort4*)(out + i) = *(const ushort4*)o4;
  }
}

// ---------------------------------------------------------------------------
// Merged Q/K/V projection GEMM. grid (16, 8, 3). 256x128 block tile, BK=32,
// 4 waves in 2x2, WAVE TILE 128x64 (acc[8][4]).
// Why: r6-r8 pinned at ~128us / MfmaUtil 19% = LDS-BW-bound (64x64 wave tile
// = 32 FLOP per LDS byte read; per-CU LDS traffic ~1150 cyc/step vs 260 cyc
// MFMA). 128x64 wave tile -> 44 FLOP/B read, 2x MFMA per barrier; MFMA work
// (~1030 cyc/block-step) now exceeds LDS traffic (~740 cyc) -> MFMA-bound.
// LDS 60 KiB (A 2x256x40, B 2x128x40). 2-deep counted-vmcnt pipeline kept:
// staging 30 granule-calls -> per-wave counts 8/8/7/7.
// ---------------------------------------------------------------------------
__global__ __launch_bounds__(256, 2) void mfma_proj(
    const u16* __restrict__ Xq, const u16* __restrict__ Xk,
    const u16* __restrict__ Xv, const u16* __restrict__ Wq,
    const u16* __restrict__ Wk, const u16* __restrict__ Wv,
    const float* __restrict__ bq, const float* __restrict__ bk,
    const float* __restrict__ bv, u16* __restrict__ Qhb,
    u16* __restrict__ Khb, u16* __restrict__ Vtb,
    const u16* __restrict__ zbuf) {
  __shared__ __attribute__((aligned(16))) u16 As2[2][256][40];
  __shared__ __attribute__((aligned(16))) u16 Bs2[2][128][40];
  const int z = blockIdx.z;
  const u16* __restrict__ Xb = (z == 0) ? Xq : (z == 1) ? Xk : Xv;
  const u16* __restrict__ Wr = (z == 0) ? Wq : (z == 1) ? Wk : Wv;
  const float* __restrict__ bias = (z == 0) ? bq : (z == 1) ? bk : bv;
  u16* __restrict__ Cptr = (z == 0) ? Qhb : (z == 1) ? Khb : Vtb;
  const int nk = (z == 2) ? 32 : 96;
  const bool conv = (z < 2);
  const bool vout = (z == 2);
  const float scale = (z == 0) ? 0.125f : 1.0f;
  const int Kdim = (z == 2) ? 1024 : 3072;

  const int tid = threadIdx.x;
  const int lane = tid & 63;
  const int w = tid >> 6;
  const int ln = tid & 15;
  const int quad = (tid >> 4) & 3;
  const int wrow = w >> 1, wcol = w & 1;
  const int m0 = blockIdx.x * 256, n0 = blockIdx.y * 128;

  // ---- hoisted per-slot staging state (slot i: c = w + 4i, c < 30) ----
  // A granules: c in [0,20) -> rows 0..255 (5 granules/row, 4 data + pad).
  // B granules: c in [20,30) -> rows 0..127.
  const char* p[8];
  int dinc[8];
  u32 ldso[8];
  bool ok[8], act[8], isA[8], loA[8], hiA[8];
  const char* pbaseA[8];

#pragma unroll
  for (int i = 0; i < 8; ++i) {
    int c = w + 4 * i;
    ok[i] = (c < 30);
    isA[i] = (c < 20);
    loA[i] = hiA[i] = false;
    pbaseA[i] = nullptr;
    if (c < 20) {
      int G = c * 64 + lane;
      int x = G / 5, kb = G - x * 5;
      int gm = m0 + x;
      int b = gm >> 11, s = gm & 2047;
      act[i] = (kb < 4);
      ldso[i] = c * 1024;
      const char* pb = (const char*)(Xb + (size_t)(b * SS + s) * DDIM + kb * 8);
      pbaseA[i] = pb;
      loA[i] = (s == 0);
      hiA[i] = (s == 2047);
      if (conv) {
        p[i] = loA[i] ? (const char*)zbuf : (pb - 2048);  // t=0: row s-1
        dinc[i] = loA[i] ? 0 : 64;
      } else {
        p[i] = pb;
        dinc[i] = 64;
      }
    } else if (c < 30) {
      int c2 = c - 20;
      int G = c2 * 64 + lane;
      int x = G / 5, kb = G - x * 5;
      act[i] = (kb < 4);
      ldso[i] = c2 * 1024;
      p[i] = (const char*)(Wr + (size_t)(n0 + x) * Kdim + kb * 8);
      dinc[i] = 64;
    } else {
      act[i] = false; ldso[i] = 0; p[i] = nullptr; dinc[i] = 0;
    }
  }

  // per-wave gld16 count per stage: w0,w1 = 8; w2,w3 = 7 (vmcnt relies on it)
  auto stage = [&](int bi) {
#pragma unroll
    for (int i = 0; i < 8; ++i) {
      if (ok[i]) {
        char* dst = (isA[i] ? (char*)As2[bi] : (char*)Bs2[bi]) + ldso[i];
        if (act[i]) gld16(p[i], dst);
        p[i] += dinc[i];
      }
    }
  };

  f32x4_t acc[8][4];
#pragma unroll
  for (int i = 0; i < 8; ++i)
#pragma unroll
    for (int j = 0; j < 4; ++j) acc[i][j] = (f32x4_t){0.f, 0.f, 0.f, 0.f};

  stage(0);  // tile 0 -> buf 0
  stage(1);  // tile 1 -> buf 1

  for (int ks = 0; ks < nk; ++ks) {
    const int cur = ks & 1;
    // wait for tile-ks loads (oldest stage); keep tile ks+1 in flight
    if (ks + 1 < nk) {
      if (w < 2) asm volatile("s_waitcnt vmcnt(8)\ns_barrier" ::: "memory");
      else       asm volatile("s_waitcnt vmcnt(7)\ns_barrier" ::: "memory");
    } else {
      asm volatile("s_waitcnt vmcnt(0)\ns_barrier" ::: "memory");
    }

    const u16(*As)[40] = As2[cur];
    const u16(*Bs)[40] = Bs2[cur];
    bf16x8_t a[8], b[4];
#pragma unroll
    for (int mt = 0; mt < 8; ++mt)
      a[mt] = *(const bf16x8_t*)&As[wrow * 128 + mt * 16 + ln][quad * 8];
#pragma unroll
    for (int nt = 0; nt < 4; ++nt)
      b[nt] = *(const bf16x8_t*)&Bs[wcol * 64 + nt * 16 + ln][quad * 8];
    // MFMAs directly after reads: compiler emits fine-grained lgkmcnt
    __builtin_amdgcn_s_setprio(1);
#pragma unroll
    for (int mt = 0; mt < 8; ++mt)
#pragma unroll
      for (int nt = 0; nt < 4; ++nt)
        acc[mt][nt] = __builtin_amdgcn_mfma_f32_16x16x32_bf16(
            a[mt], b[nt], acc[mt][nt], 0, 0, 0);
    __builtin_amdgcn_s_setprio(0);

    asm volatile("s_waitcnt lgkmcnt(0)\ns_barrier" ::: "memory");
    __builtin_amdgcn_sched_barrier(0);  // keep reads/MFMA above this point

    const int j = ks + 2;
    if (j < nk) {
      if (conv && (j & 31) == 0) {  // staged tile crosses a t-phase boundary
#pragma unroll
        for (int i = 0; i < 8; ++i) {
          if (ok[i] && isA[i]) {
            if (j == 32) {  // entering t=1: unfreeze s==0 rows
              if (loA[i]) { p[i] = pbaseA[i]; dinc[i] = 64; }
            } else {        // entering t=2: freeze s==2047 rows
              if (hiA[i]) { p[i] = (const char*)zbuf; dinc[i] = 0; }
            }
          }
        }
      }
      stage(cur);  // tile ks+2 -> just-freed buffer; flies over iter ks+1
    }
  }

#pragma unroll
  for (int mt = 0; mt < 8; ++mt) {
#pragma unroll
    for (int nt = 0; nt < 4; ++nt) {
      int gn = n0 + wcol * 64 + nt * 16 + ln;
      float bi = bias[gn];
#pragma unroll
      for (int r = 0; r < 4; ++r) {
        int gm = m0 + wrow * 128 + mt * 16 + quad * 4 + r;
        float val = (acc[mt][nt][r] + bi) * scale;
        int b = gm >> 11, s = gm & 2047;
        int hh = gn & 15, dd = gn >> 4;  // channel = dd*16 + hh (head FAST)
        if (!vout)
          Cptr[((size_t)(b * 16 + hh) * SS + s) * 64 + dd] = f2bf(val);
        else
          Cptr[((size_t)(b * 16 + hh) * 64 + dd) * SS + s] = f2bf(val);
      }
    }
  }
}

// ---------------------------------------------------------------------------
// Final linear GEMM. 32x128 tile, grid (128, 8). (unchanged from r8)
// ---------------------------------------------------------------------------
__global__ __launch_bounds__(256) void mfma_gemm_lin(
    const u16* __restrict__ Xb, const u16* __restrict__ Wr,
    const float* __restrict__ bias, float* __restrict__ Cptr) {
  __shared__ __attribute__((aligned(16))) u16 As2[2][32][40];
  __shared__ __attribute__((aligned(16))) u16 Bs2[2][128][40];
  const int tid = threadIdx.x;
  const int lane = tid & 63;
  const int w = tid >> 6;
  const int ln = tid & 15;
  const int quad = (tid >> 4) & 3;
  const int wrow = w >> 1, wcol = w & 1;
  const int m0 = blockIdx.x * 32, n0 = blockIdx.y * 128;

  const char* p[4];
  u32 ldso[4];
  bool ok[4], act[4], isA[4];
#pragma unroll
  for (int i = 0; i < 4; ++i) {
    int c = w + 4 * i;
    ok[i] = (c < 13);
    if (c < 3) {
      int G = c * 64 + lane;
      int x = G / 5, kb = G - x * 5;
      isA[i] = true;
      act[i] = (kb < 4) && (x < 32);
      ldso[i] = c * 1024;
      p[i] = (const char*)(Xb + (size_t)(m0 + x) * DDIM + kb * 8);
    } else if (c < 13) {
      int c2 = c - 3;
      int G = c2 * 64 + lane;
      int x = G / 5, kb = G - x * 5;
      isA[i] = false;
      act[i] = (kb < 4);
      ldso[i] = c2 * 1024;
      p[i] = (const char*)(Wr + (size_t)(n0 + x) * 1024 + kb * 8);
    } else {
      isA[i] = false; act[i] = false; ldso[i] = 0; p[i] = nullptr;
    }
  }

  auto stage = [&](int bi) {
#pragma unroll
    for (int i = 0; i < 4; ++i) {
      if (ok[i]) {
        char* dst = (isA[i] ? (char*)As2[bi] : (char*)Bs2[bi]) + ldso[i];
        if (act[i]) gld16(p[i], dst);
        p[i] += 64;
      }
    }
  };

  f32x4_t acc[4];
#pragma unroll
  for (int j = 0; j < 4; ++j) acc[j] = (f32x4_t){0.f, 0.f, 0.f, 0.f};

  stage(0);
  stage(1);

#pragma unroll 2
  for (int ks = 0; ks < 32; ++ks) {
    const int cur = ks & 1;
    if (ks + 1 < 32) {
      if (w == 0) asm volatile("s_waitcnt vmcnt(4)\ns_barrier" ::: "memory");
      else        asm volatile("s_waitcnt vmcnt(3)\ns_barrier" ::: "memory");
    } else {
      asm volatile("s_waitcnt vmcnt(0)\ns_barrier" ::: "memory");
    }

    const u16(*As)[40] = As2[cur];
    const u16(*Bs)[40] = Bs2[cur];
    bf16x8_t a = *(const bf16x8_t*)&As[wrow * 16 + ln][quad * 8];
    bf16x8_t b[4];
#pragma unroll
    for (int nt = 0; nt < 4; ++nt)
      b[nt] = *(const bf16x8_t*)&Bs[wcol * 64 + nt * 16 + ln][quad * 8];
    __builtin_amdgcn_s_setprio(1);
#pragma unroll
    for (int nt = 0; nt < 4; ++nt)
      acc[nt] = __builtin_amdgcn_mfma_f32_16x16x32_bf16(a, b[nt], acc[nt], 0, 0, 0);
    __builtin_amdgcn_s_setprio(0);

    asm volatile("s_waitcnt lgkmcnt(0)\ns_barrier" ::: "memory");
    __builtin_amdgcn_sched_barrier(0);

    if (ks + 2 < 32) stage(cur);
  }

#pragma unroll
  for (int nt = 0; nt < 4; ++nt) {
    int gn = n0 + wcol * 64 + nt * 16 + ln;
    float bi = bias[gn];
#pragma unroll
    for (int r = 0; r < 4; ++r) {
      int gm = m0 + wrow * 16 + quad * 4 + r;
      Cptr[(size_t)gm * DDIM + gn] = acc[nt][r] + bi;
    }
  }
}

// ---------------------------------------------------------------------------
// MFMA flash attention (unchanged from r8: wave-shared max, 2-deep pipeline).
// ---------------------------------------------------------------------------
__global__ __launch_bounds__(256) void mfma_attn(
    const u16* __restrict__ Qhb, const u16* __restrict__ Khb,
    const u16* __restrict__ Vtb, u16* __restrict__ Aob,
    const u16* __restrict__ zbuf) {
  __shared__ __attribute__((aligned(16))) u16 Ks2[2][64][72];
  __shared__ __attribute__((aligned(16))) u16 Vt2[2][64][72];
  __shared__ __attribute__((aligned(16))) u16 Ps[4][16][72];
  const int tid = threadIdx.x;
  const int lane = tid & 63;
  const int w = tid >> 6;
  const int ln = tid & 15;
  const int quad = (tid >> 4) & 3;
  const int bh = blockIdx.y;
  const int b = bh >> 4, hh = bh & 15;
  const int s0 = blockIdx.x * 64;

  const char* p[5];
  int dinc[5];
  u32 ldso[5];
  bool ok[5], act[5], isK[5];
#pragma unroll
  for (int i = 0; i < 5; ++i) {
    int c = w + 4 * i;
    ok[i] = (c < 18);
    if (c < 9) {
      int G = c * 64 + lane;
      int x = G / 9, db = G - x * 9;
      isK[i] = true;
      act[i] = (db < 8);
      ldso[i] = c * 1024;
      p[i] = (const char*)(Khb + ((size_t)bh * SS + x) * 64 + db * 8);
      dinc[i] = 8192;
    } else if (c < 18) {
      int c2 = c - 9;
      int G = c2 * 64 + lane;
      int x = G / 9, db = G - x * 9;
      isK[i] = false;
      act[i] = (db < 8);
      ldso[i] = c2 * 1024;
      p[i] = (const char*)(Vtb + ((size_t)bh * 64 + x) * SS + db * 8);
      dinc[i] = 128;
    } else {
      isK[i] = false; ok[i] = false; act[i] = false; ldso[i] = 0;
      p[i] = nullptr; dinc[i] = 0;
    }
  }

  auto stage = [&](int bi) {
#pragma unroll
    for (int i = 0; i < 5; ++i) {
      if (ok[i]) {
        char* dst = (isK[i] ? (char*)Ks2[bi] : (char*)Vt2[bi]) + ldso[i];
        if (act[i]) gld16(p[i], dst);
        p[i] += dinc[i];
      }
    }
  };

  const u16* qp = Qhb + ((size_t)bh * SS + s0 + w * 16 + ln) * 64 + quad * 8;
  bf16x8_t qf0 = *(const bf16x8_t*)qp;
  bf16x8_t qf1 = *(const bf16x8_t*)(qp + 32);

  float mrow = -3e38f;  // wave-shared running max
  float lsum[4];
  f32x4_t oacc[4];
#pragma unroll
  for (int r = 0; r < 4; ++r) lsum[r] = 0.f;
#pragma unroll
  for (int dt = 0; dt < 4; ++dt) oacc[dt] = (f32x4_t){0.f, 0.f, 0.f, 0.f};

  stage(0);
  stage(1);

#pragma unroll 2
  for (int kt = 0; kt < 32; ++kt) {
    const int cur = kt & 1;
    if (kt + 1 < 32) {
      if (w < 2) asm volatile("s_waitcnt vmcnt(5)\ns_barrier" ::: "memory");
      else       asm volatile("s_waitcnt vmcnt(4)\ns_barrier" ::: "memory");
    } else {
      asm volatile("s_waitcnt vmcnt(0)\ns_barrier" ::: "memory");
    }

    const u16(*Ks)[72] = Ks2[cur];
    const u16(*Vt)[72] = Vt2[cur];

    f32x4_t sc[4];
#pragma unroll
    for (int nt = 0; nt < 4; ++nt) sc[nt] = (f32x4_t){0.f, 0.f, 0.f, 0.f};
    __builtin_amdgcn_s_setprio(1);
#pragma unroll
    for (int nt = 0; nt < 4; ++nt) {
      bf16x8_t k0f = *(const bf16x8_t*)&Ks[nt * 16 + ln][quad * 8];
      sc[nt] = __builtin_amdgcn_mfma_f32_16x16x32_bf16(qf0, k0f, sc[nt], 0, 0, 0);
      bf16x8_t k1f = *(const bf16x8_t*)&Ks[nt * 16 + ln][32 + quad * 8];
      sc[nt] = __builtin_amdgcn_mfma_f32_16x16x32_bf16(qf1, k1f, sc[nt], 0, 0, 0);
    }
    __builtin_amdgcn_s_setprio(0);

    // wave-shared max: local max over 16 regs, then 6-shfl full-wave reduce
    float mx = sc[0][0];
#pragma unroll
    for (int nt = 0; nt < 4; ++nt)
#pragma unroll
      for (int r = 0; r < 4; ++r) mx = fmaxf(mx, sc[nt][r]);
    mx = fmaxf(mx, __shfl_xor(mx, 1, 64));
    mx = fmaxf(mx, __shfl_xor(mx, 2, 64));
    mx = fmaxf(mx, __shfl_xor(mx, 4, 64));
    mx = fmaxf(mx, __shfl_xor(mx, 8, 64));
    mx = fmaxf(mx, __shfl_xor(mx, 16, 64));
    mx = fmaxf(mx, __shfl_xor(mx, 32, 64));
    if (mx > mrow) {  // wave-uniform branch
      float al = __expf(mrow - mx);
      mrow = mx;
#pragma unroll
      for (int r = 0; r < 4; ++r) lsum[r] *= al;
#pragma unroll
      for (int dt = 0; dt < 4; ++dt)
#pragma unroll
        for (int r = 0; r < 4; ++r) oacc[dt][r] *= al;
    }
#pragma unroll
    for (int r = 0; r < 4; ++r) {
      float p0 = __expf(sc[0][r] - mrow), p1 = __expf(sc[1][r] - mrow);
      float p2 = __expf(sc[2][r] - mrow), p3 = __expf(sc[3][r] - mrow);
      lsum[r] += p0 + p1 + p2 + p3;
      Ps[w][quad * 4 + r][ln] = f2bf(p0);
      Ps[w][quad * 4 + r][16 + ln] = f2bf(p1);
      Ps[w][quad * 4 + r][32 + ln] = f2bf(p2);
      Ps[w][quad * 4 + r][48 + ln] = f2bf(p3);
    }

    // PV (P read back in A-operand layout; same-wave LDS program order)
    bf16x8_t pa0 = *(const bf16x8_t*)&Ps[w][ln][quad * 8];
    bf16x8_t pa1 = *(const bf16x8_t*)&Ps[w][ln][32 + quad * 8];
    __builtin_amdgcn_s_setprio(1);
#pragma unroll
    for (int dt = 0; dt < 4; ++dt) {
      bf16x8_t v0f = *(const bf16x8_t*)&Vt[dt * 16 + ln][quad * 8];
      oacc[dt] = __builtin_amdgcn_mfma_f32_16x16x32_bf16(pa0, v0f, oacc[dt], 0, 0, 0);
      bf16x8_t v1f = *(const bf16x8_t*)&Vt[dt * 16 + ln][32 + quad * 8];
      oacc[dt] = __builtin_amdgcn_mfma_f32_16x16x32_bf16(pa1, v1f, oacc[dt], 0, 0, 0);
    }
    __builtin_amdgcn_s_setprio(0);

    asm volatile("s_waitcnt lgkmcnt(0)\ns_barrier" ::: "memory");
    __builtin_amdgcn_sched_barrier(0);
    if (kt + 2 < 32) stage(cur);  // tile kt+2; flies over all of iter kt+1
  }

  // epilogue: reduce lane-partial sums once, normalize, store
  float inv[4];
#pragma unroll
  for (int r = 0; r < 4; ++r) {
    float t = lsum[r];
    t += __shfl_xor(t, 1, 64);
    t += __shfl_xor(t, 2, 64);
    t += __shfl_xor(t, 4, 64);
    t += __shfl_xor(t, 8, 64);
    inv[r] = 1.f / t;
  }
#pragma unroll
  for (int dt = 0; dt < 4; ++dt)
#pragma unroll
    for (int r = 0; r < 4; ++r) {
      int gm = b * SS + s0 + w * 16 + quad * 4 + r;
      Aob[(size_t)gm * DDIM + hh * 64 + dt * 16 + ln] = f2bf(oacc[dt][r] * inv[r]);
    }
}

// ---------------------------------------------------------------------------
// Launch
// ---------------------------------------------------------------------------
extern "C" void kernel_launch(void* const* d_in, const int* in_sizes, int n_in,
                              void* d_out, int out_size, void* d_ws, size_t ws_size,
                              hipStream_t stream) {
  const float* q    = (const float*)d_in[0];
  const float* k    = (const float*)d_in[1];
  const float* v    = (const float*)d_in[2];
  const float* wq_w = (const float*)d_in[3];
  const float* wq_b = (const float*)d_in[4];
  const float* wk_w = (const float*)d_in[5];
  const float* wk_b = (const float*)d_in[6];
  const float* wv_w = (const float*)d_in[7];
  const float* wv_b = (const float*)d_in[8];
  const float* wc_w = (const float*)d_in[9];
  const float* wc_b = (const float*)d_in[10];

  char* ws = (char*)d_ws;
  size_t off = 0;
  u16* zbuf = (u16*)(ws + off); off += 256;
  const size_t SZ_ACT = (size_t)2 * SS * DDIM * 2;  // 8 MB bf16
  u16* Xq  = (u16*)(ws + off); off += SZ_ACT;
  u16* Xk  = (u16*)(ws + off); off += SZ_ACT;
  u16* Xv  = (u16*)(ws + off); off += SZ_ACT;
  u16* Wqr = (u16*)(ws + off); off += (size_t)1024 * 3072 * 2;
  u16* Wkr = (u16*)(ws + off); off += (size_t)1024 * 3072 * 2;
  u16* Wvr = (u16*)(ws + off); off += (size_t)1024 * 1024 * 2;
  u16* Wcr = (u16*)(ws + off); off += (size_t)1024 * 1024 * 2;
  u16* Qhb = (u16*)(ws + off); off += SZ_ACT;
  u16* Khb = (u16*)(ws + off); off += SZ_ACT;
  u16* Vtb = (u16*)(ws + off); off += SZ_ACT;
  u16* Aob = (u16*)(ws + off); off += SZ_ACT;
  if (ws_size < off) return;

  prep_kernel<<<10240, 256, 0, stream>>>(q, k, v, wq_w, wk_w, wv_w, wc_w,
                                         Xq, Xk, Xv, Wqr, Wkr, Wvr, Wcr,
                                         (u32*)zbuf);

  // merged Q/K/V projections: 256x128 tile, 128x64 wave tile
  mfma_proj<<<dim3(16, 8, 3), 256, 0, stream>>>(
      Xq, Xk, Xv, Wqr, Wkr, Wvr, wq_b, wk_b, wv_b, Qhb, Khb, Vtb, zbuf);

  mfma_attn<<<dim3(32, 32), 256, 0, stream>>>(Qhb, Khb, Vtb, Aob, zbuf);

  mfma_gemm_lin<<<dim3(128, 8), 256, 0, stream>>>(Aob, Wcr, wc_b, (float*)d_out);
}

// Round 10
// 379.224 us; speedup vs baseline: 1.0041x; 1.0041x over previous
//
#include <hip/hip_runtime.h>
#include <hip/hip_bf16.h>

#define SS 2048
#define DDIM 1024

typedef unsigned short u16;
typedef unsigned int u32;
typedef __attribute__((ext_vector_type(8))) short bf16x8_t;
typedef __attribute__((ext_vector_type(4))) float f32x4_t;

__device__ __forceinline__ u16 f2bf(float f) {
  __hip_bfloat16 h = __float2bfloat16(f);
  return *reinterpret_cast<u16*>(&h);
}

// async global->LDS, 16 B per lane. LDS dest = (wave-uniform) base + lane*16.
__device__ __forceinline__ void gld16(const void* g, void* lds_base) {
  __builtin_amdgcn_global_load_lds(
      (const __attribute__((address_space(1))) u32*)(uintptr_t)g,
      (__attribute__((address_space(3))) u32*)(u32)(uintptr_t)lds_base,
      16, 0, 0);
}

// ---------------------------------------------------------------------------
// Fused prep: zbuf zero + f32->bf16 converts + weight repacks. Grid 10240.
// ---------------------------------------------------------------------------
__global__ __launch_bounds__(256) void prep_kernel(
    const float* __restrict__ q, const float* __restrict__ k,
    const float* __restrict__ v, const float* __restrict__ wq_w,
    const float* __restrict__ wk_w, const float* __restrict__ wv_w,
    const float* __restrict__ wc_w, u16* __restrict__ Xq,
    u16* __restrict__ Xk, u16* __restrict__ Xv, u16* __restrict__ Wqr,
    u16* __restrict__ Wkr, u16* __restrict__ Wvr, u16* __restrict__ Wcr,
    u32* __restrict__ zbuf) {
  const int bid = blockIdx.x;
  const int tid = threadIdx.x;
  if (bid == 0 && tid < 64) zbuf[tid] = 0u;

  if (bid < 6144) {
    const int z = bid >> 11;            // 0..2
    const int bx = bid & 2047;
    const float* src = (z == 0) ? q : (z == 1) ? k : v;
    u16* dst = (z == 0) ? Xq : (z == 1) ? Xk : Xv;
    int i = bx * 256 + tid;
    const float4* s = (const float4*)src + (size_t)i * 2;
    float4 f0 = s[0], f1 = s[1];
    u16 o[8] = {f2bf(f0.x), f2bf(f0.y), f2bf(f0.z), f2bf(f0.w),
                f2bf(f1.x), f2bf(f1.y), f2bf(f1.z), f2bf(f1.w)};
    *(uint4*)(dst + (size_t)i * 8) = *(const uint4*)o;
  } else if (bid < 8192) {
    const int idx = bid - 6144;
    const float* w = (idx >= 1024) ? wk_w : wq_w;
    u16* out = (idx >= 1024) ? Wkr : Wqr;
    const int o = idx & 1023;
    for (int j = tid; j < 3072; j += 256) {
      int i = j / 3, t = j - i * 3;
      out[(size_t)o * 3072 + t * 1024 + i] = f2bf(w[(size_t)o * 3072 + j]);
    }
  } else {
    const int idx = bid - 8192;
    const float* w = (idx >= 1024) ? wc_w : wv_w;
    u16* out = (idx >= 1024) ? Wcr : Wvr;
    const int bx = idx & 1023;
    size_t i = (size_t)bx * 1024 + tid * 4;
    float4 f = *(const float4*)(w + i);
    u16 o4[4] = {f2bf(f.x), f2bf(f.y), f2bf(f.z), f2bf(f.w)};
    *(ushort4*)(out + i) = *(const ushort4*)o4;
  }
}

// ---------------------------------------------------------------------------
// Merged Q/K/V projection GEMM. grid (32, 8, 3). 128x128 tile, BK=32
// (the best-measured geometry). DEPTH-3 counted-vmcnt pipeline: prologue
// stages tiles 0..2 into 3 LDS buffers (60 KB); iter ks waits vmcnt(10)
// (= 2 stages x 5 gld16/wave still in flight -> the consumed tile's loads
// got ~2.5 iterations ~= HBM latency of flight), refills buf with tile
// ks+3 at the bottom. r9 disproved LDS-BW theory; r6-r9 counters show the
// ~80% idle is un-hidden HBM latency (FETCH ~2x inputs, ~900 cyc misses).
// ---------------------------------------------------------------------------
__global__ __launch_bounds__(256) void mfma_proj(
    const u16* __restrict__ Xq, const u16* __restrict__ Xk,
    const u16* __restrict__ Xv, const u16* __restrict__ Wq,
    const u16* __restrict__ Wk, const u16* __restrict__ Wv,
    const float* __restrict__ bq, const float* __restrict__ bk,
    const float* __restrict__ bv, u16* __restrict__ Qhb,
    u16* __restrict__ Khb, u16* __restrict__ Vtb,
    const u16* __restrict__ zbuf, float qscale) {
  __shared__ __attribute__((aligned(16))) u16 As3[3][128][40];
  __shared__ __attribute__((aligned(16))) u16 Bs3[3][128][40];
  const int z = blockIdx.z;
  const u16* __restrict__ Xb = (z == 0) ? Xq : (z == 1) ? Xk : Xv;
  const u16* __restrict__ Wr = (z == 0) ? Wq : (z == 1) ? Wk : Wv;
  const float* __restrict__ bias = (z == 0) ? bq : (z == 1) ? bk : bv;
  u16* __restrict__ Cptr = (z == 0) ? Qhb : (z == 1) ? Khb : Vtb;
  const int nk = (z == 2) ? 32 : 96;
  const bool conv = (z < 2);
  const bool vout = (z == 2);
  const float scale = (z == 0) ? qscale : 1.0f;
  const int Kdim = (z == 2) ? 1024 : 3072;

  const int tid = threadIdx.x;
  const int lane = tid & 63;
  const int w = tid >> 6;
  const int ln = tid & 15;
  const int quad = (tid >> 4) & 3;
  const int wrow = w >> 1, wcol = w & 1;
  const int m0 = blockIdx.x * 128, n0 = blockIdx.y * 128;

  // ---- hoisted per-slot staging state (slot i: c = w + 4i, c < 20) ----
  const char* p[5];
  int dinc[5];
  u32 ldso[5];
  bool act[5], isA[5], loA[5], hiA[5];
  const char* pbaseA[5];

#pragma unroll
  for (int i = 0; i < 5; ++i) {
    int c = w + 4 * i;
    isA[i] = (c < 10);
    loA[i] = hiA[i] = false;
    pbaseA[i] = nullptr;
    if (c < 10) {
      int G = c * 64 + lane;
      int x = G / 5, kb = G - x * 5;
      int gm = m0 + x;
      int b = gm >> 11, s = gm & 2047;
      act[i] = (kb < 4);
      ldso[i] = c * 1024;
      const char* pb = (const char*)(Xb + (size_t)(b * SS + s) * DDIM + kb * 8);
      pbaseA[i] = pb;
      loA[i] = (s == 0);
      hiA[i] = (s == 2047);
      if (conv) {
        p[i] = loA[i] ? (const char*)zbuf : (pb - 2048);  // t=0: row s-1
        dinc[i] = loA[i] ? 0 : 64;
      } else {
        p[i] = pb;
        dinc[i] = 64;
      }
    } else {
      int c2 = c - 10;
      int G = c2 * 64 + lane;
      int x = G / 5, kb = G - x * 5;
      act[i] = (kb < 4);
      ldso[i] = c2 * 1024;
      p[i] = (const char*)(Wr + (size_t)(n0 + x) * Kdim + kb * 8);
      dinc[i] = 64;
    }
  }

  // each call issues EXACTLY 5 gld16 per wave (every slot has active lanes)
  auto stage = [&](int bi) {
#pragma unroll
    for (int i = 0; i < 5; ++i) {
      char* dst = (isA[i] ? (char*)As3[bi] : (char*)Bs3[bi]) + ldso[i];
      if (act[i]) gld16(p[i], dst);
      p[i] += dinc[i];
    }
  };

  f32x4_t acc[4][4];
#pragma unroll
  for (int i = 0; i < 4; ++i)
#pragma unroll
    for (int j = 0; j < 4; ++j) acc[i][j] = (f32x4_t){0.f, 0.f, 0.f, 0.f};

  stage(0);  // tile 0 -> buf 0
  stage(1);  // tile 1 -> buf 1
  stage(2);  // tile 2 -> buf 2 (15 outstanding/wave)

  int cur = 0;
  for (int ks = 0; ks < nk; ++ks) {
    const int rem = nk - ks;
    // wait for tile ks (oldest); keep up to 2 staged tiles in flight
    if (rem >= 3)      asm volatile("s_waitcnt vmcnt(10)\ns_barrier" ::: "memory");
    else if (rem == 2) asm volatile("s_waitcnt vmcnt(5)\ns_barrier" ::: "memory");
    else               asm volatile("s_waitcnt vmcnt(0)\ns_barrier" ::: "memory");

    const u16(*As)[40] = As3[cur];
    const u16(*Bs)[40] = Bs3[cur];
    bf16x8_t a[4], b[4];
#pragma unroll
    for (int mt = 0; mt < 4; ++mt)
      a[mt] = *(const bf16x8_t*)&As[wrow * 64 + mt * 16 + ln][quad * 8];
#pragma unroll
    for (int nt = 0; nt < 4; ++nt)
      b[nt] = *(const bf16x8_t*)&Bs[wcol * 64 + nt * 16 + ln][quad * 8];
    // MFMAs directly after reads: compiler emits fine-grained lgkmcnt
    __builtin_amdgcn_s_setprio(1);
#pragma unroll
    for (int mt = 0; mt < 4; ++mt)
#pragma unroll
      for (int nt = 0; nt < 4; ++nt)
        acc[mt][nt] = __builtin_amdgcn_mfma_f32_16x16x32_bf16(
            a[mt], b[nt], acc[mt][nt], 0, 0, 0);
    __builtin_amdgcn_s_setprio(0);

    asm volatile("s_waitcnt lgkmcnt(0)\ns_barrier" ::: "memory");
    __builtin_amdgcn_sched_barrier(0);  // keep reads/MFMA above this point

    const int j = ks + 3;
    if (j < nk) {
      if (conv && (j & 31) == 0) {  // staged tile crosses a t-phase boundary
#pragma unroll
        for (int i = 0; i < 5; ++i) {
          if (isA[i]) {
            if (j == 32) {  // entering t=1: unfreeze s==0 rows
              if (loA[i]) { p[i] = pbaseA[i]; dinc[i] = 64; }
            } else {        // entering t=2: freeze s==2047 rows
              if (hiA[i]) { p[i] = (const char*)zbuf; dinc[i] = 0; }
            }
          }
        }
      }
      stage(cur);  // tile ks+3 -> just-freed buffer; flies ~2.5 iterations
    }
    cur = (cur == 2) ? 0 : cur + 1;
  }

#pragma unroll
  for (int mt = 0; mt < 4; ++mt) {
#pragma unroll
    for (int nt = 0; nt < 4; ++nt) {
      int gn = n0 + wcol * 64 + nt * 16 + ln;
      float bi = bias[gn];
#pragma unroll
      for (int r = 0; r < 4; ++r) {
        int gm = m0 + wrow * 64 + mt * 16 + quad * 4 + r;
        float val = (acc[mt][nt][r] + bi) * scale;
        int b = gm >> 11, s = gm & 2047;
        int hh = gn & 15, dd = gn >> 4;  // channel = dd*16 + hh (head FAST)
        if (!vout)
          Cptr[((size_t)(b * 16 + hh) * SS + s) * 64 + dd] = f2bf(val);
        else
          Cptr[((size_t)(b * 16 + hh) * 64 + dd) * SS + s] = f2bf(val);
      }
    }
  }
}

// ---------------------------------------------------------------------------
// Final linear GEMM. 32x128 tile, grid (128, 8). Depth-3 pipeline.
// Per-wave stage counts: w0=4, w1..3=3.
// ---------------------------------------------------------------------------
__global__ __launch_bounds__(256) void mfma_gemm_lin(
    const u16* __restrict__ Xb, const u16* __restrict__ Wr,
    const float* __restrict__ bias, float* __restrict__ Cptr) {
  __shared__ __attribute__((aligned(16))) u16 As3[3][32][40];
  __shared__ __attribute__((aligned(16))) u16 Bs3[3][128][40];
  const int tid = threadIdx.x;
  const int lane = tid & 63;
  const int w = tid >> 6;
  const int ln = tid & 15;
  const int quad = (tid >> 4) & 3;
  const int wrow = w >> 1, wcol = w & 1;
  const int m0 = blockIdx.x * 32, n0 = blockIdx.y * 128;

  const char* p[4];
  u32 ldso[4];
  bool ok[4], act[4], isA[4];
#pragma unroll
  for (int i = 0; i < 4; ++i) {
    int c = w + 4 * i;
    ok[i] = (c < 13);
    if (c < 3) {
      int G = c * 64 + lane;
      int x = G / 5, kb = G - x * 5;
      isA[i] = true;
      act[i] = (kb < 4) && (x < 32);
      ldso[i] = c * 1024;
      p[i] = (const char*)(Xb + (size_t)(m0 + x) * DDIM + kb * 8);
    } else if (c < 13) {
      int c2 = c - 3;
      int G = c2 * 64 + lane;
      int x = G / 5, kb = G - x * 5;
      isA[i] = false;
      act[i] = (kb < 4);
      ldso[i] = c2 * 1024;
      p[i] = (const char*)(Wr + (size_t)(n0 + x) * 1024 + kb * 8);
    } else {
      isA[i] = false; act[i] = false; ldso[i] = 0; p[i] = nullptr;
    }
  }

  auto stage = [&](int bi) {
#pragma unroll
    for (int i = 0; i < 4; ++i) {
      if (ok[i]) {
        char* dst = (isA[i] ? (char*)As3[bi] : (char*)Bs3[bi]) + ldso[i];
        if (act[i]) gld16(p[i], dst);
        p[i] += 64;
      }
    }
  };

  f32x4_t acc[4];
#pragma unroll
  for (int j = 0; j < 4; ++j) acc[j] = (f32x4_t){0.f, 0.f, 0.f, 0.f};

  stage(0);
  stage(1);
  stage(2);

  int cur = 0;
  for (int ks = 0; ks < 32; ++ks) {
    const int rem = 32 - ks;
    if (rem >= 3) {
      if (w == 0) asm volatile("s_waitcnt vmcnt(8)\ns_barrier" ::: "memory");
      else        asm volatile("s_waitcnt vmcnt(6)\ns_barrier" ::: "memory");
    } else if (rem == 2) {
      if (w == 0) asm volatile("s_waitcnt vmcnt(4)\ns_barrier" ::: "memory");
      else        asm volatile("s_waitcnt vmcnt(3)\ns_barrier" ::: "memory");
    } else {
      asm volatile("s_waitcnt vmcnt(0)\ns_barrier" ::: "memory");
    }

    const u16(*As)[40] = As3[cur];
    const u16(*Bs)[40] = Bs3[cur];
    bf16x8_t a = *(const bf16x8_t*)&As[wrow * 16 + ln][quad * 8];
    bf16x8_t b[4];
#pragma unroll
    for (int nt = 0; nt < 4; ++nt)
      b[nt] = *(const bf16x8_t*)&Bs[wcol * 64 + nt * 16 + ln][quad * 8];
    __builtin_amdgcn_s_setprio(1);
#pragma unroll
    for (int nt = 0; nt < 4; ++nt)
      acc[nt] = __builtin_amdgcn_mfma_f32_16x16x32_bf16(a, b[nt], acc[nt], 0, 0, 0);
    __builtin_amdgcn_s_setprio(0);

    asm volatile("s_waitcnt lgkmcnt(0)\ns_barrier" ::: "memory");
    __builtin_amdgcn_sched_barrier(0);

    if (ks + 3 < 32) stage(cur);
    cur = (cur == 2) ? 0 : cur + 1;
  }

#pragma unroll
  for (int nt = 0; nt < 4; ++nt) {
    int gn = n0 + wcol * 64 + nt * 16 + ln;
    float bi = bias[gn];
#pragma unroll
    for (int r = 0; r < 4; ++r) {
      int gm = m0 + wrow * 16 + quad * 4 + r;
      Cptr[(size_t)gm * DDIM + gn] = acc[nt][r] + bi;
    }
  }
}

// ---------------------------------------------------------------------------
// MFMA flash attention. Depth-3 K/V pipeline (LDS 64.5 KB); exp2 softmax:
// Q was pre-scaled by 0.125*log2(e) at projection, so P = 2^(S - m) ==
// e^(S_orig/8 - m_orig) exactly (max/sum are monotone-invariant; Q rounding
// error class unchanged: one bf16 round). Saves the hidden *log2e mul in
// all 17 exps/tile. Wave-shared max kept from r8.
// Per-wave stage counts: w0,w1=5; w2,w3=4.
// ---------------------------------------------------------------------------
__global__ __launch_bounds__(256) void mfma_attn(
    const u16* __restrict__ Qhb, const u16* __restrict__ Khb,
    const u16* __restrict__ Vtb, u16* __restrict__ Aob,
    const u16* __restrict__ zbuf) {
  __shared__ __attribute__((aligned(16))) u16 Ks3[3][64][72];
  __shared__ __attribute__((aligned(16))) u16 Vt3[3][64][72];
  __shared__ __attribute__((aligned(16))) u16 Ps[4][16][72];
  const int tid = threadIdx.x;
  const int lane = tid & 63;
  const int w = tid >> 6;
  const int ln = tid & 15;
  const int quad = (tid >> 4) & 3;
  const int bh = blockIdx.y;
  const int b = bh >> 4, hh = bh & 15;
  const int s0 = blockIdx.x * 64;

  const char* p[5];
  int dinc[5];
  u32 ldso[5];
  bool ok[5], act[5], isK[5];
#pragma unroll
  for (int i = 0; i < 5; ++i) {
    int c = w + 4 * i;
    ok[i] = (c < 18);
    if (c < 9) {
      int G = c * 64 + lane;
      int x = G / 9, db = G - x * 9;
      isK[i] = true;
      act[i] = (db < 8);
      ldso[i] = c * 1024;
      p[i] = (const char*)(Khb + ((size_t)bh * SS + x) * 64 + db * 8);
      dinc[i] = 8192;
    } else if (c < 18) {
      int c2 = c - 9;
      int G = c2 * 64 + lane;
      int x = G / 9, db = G - x * 9;
      isK[i] = false;
      act[i] = (db < 8);
      ldso[i] = c2 * 1024;
      p[i] = (const char*)(Vtb + ((size_t)bh * 64 + x) * SS + db * 8);
      dinc[i] = 128;
    } else {
      isK[i] = false; ok[i] = false; act[i] = false; ldso[i] = 0;
      p[i] = nullptr; dinc[i] = 0;
    }
  }

  auto stage = [&](int bi) {
#pragma unroll
    for (int i = 0; i < 5; ++i) {
      if (ok[i]) {
        char* dst = (isK[i] ? (char*)Ks3[bi] : (char*)Vt3[bi]) + ldso[i];
        if (act[i]) gld16(p[i], dst);
        p[i] += dinc[i];
      }
    }
  };

  const u16* qp = Qhb + ((size_t)bh * SS + s0 + w * 16 + ln) * 64 + quad * 8;
  bf16x8_t qf0 = *(const bf16x8_t*)qp;
  bf16x8_t qf1 = *(const bf16x8_t*)(qp + 32);

  float mrow = -3e38f;  // wave-shared running max (log2 domain)
  float lsum[4];
  f32x4_t oacc[4];
#pragma unroll
  for (int r = 0; r < 4; ++r) lsum[r] = 0.f;
#pragma unroll
  for (int dt = 0; dt < 4; ++dt) oacc[dt] = (f32x4_t){0.f, 0.f, 0.f, 0.f};

  stage(0);
  stage(1);
  stage(2);

  int cur = 0;
  for (int kt = 0; kt < 32; ++kt) {
    const int rem = 32 - kt;
    if (rem >= 3) {
      if (w < 2) asm volatile("s_waitcnt vmcnt(10)\ns_barrier" ::: "memory");
      else       asm volatile("s_waitcnt vmcnt(8)\ns_barrier" ::: "memory");
    } else if (rem == 2) {
      if (w < 2) asm volatile("s_waitcnt vmcnt(5)\ns_barrier" ::: "memory");
      else       asm volatile("s_waitcnt vmcnt(4)\ns_barrier" ::: "memory");
    } else {
      asm volatile("s_waitcnt vmcnt(0)\ns_barrier" ::: "memory");
    }

    const u16(*Ks)[72] = Ks3[cur];
    const u16(*Vt)[72] = Vt3[cur];

    f32x4_t sc[4];
#pragma unroll
    for (int nt = 0; nt < 4; ++nt) sc[nt] = (f32x4_t){0.f, 0.f, 0.f, 0.f};
    __builtin_amdgcn_s_setprio(1);
#pragma unroll
    for (int nt = 0; nt < 4; ++nt) {
      bf16x8_t k0f = *(const bf16x8_t*)&Ks[nt * 16 + ln][quad * 8];
      sc[nt] = __builtin_amdgcn_mfma_f32_16x16x32_bf16(qf0, k0f, sc[nt], 0, 0, 0);
      bf16x8_t k1f = *(const bf16x8_t*)&Ks[nt * 16 + ln][32 + quad * 8];
      sc[nt] = __builtin_amdgcn_mfma_f32_16x16x32_bf16(qf1, k1f, sc[nt], 0, 0, 0);
    }
    __builtin_amdgcn_s_setprio(0);

    // wave-shared max: local max over 16 regs, then 6-shfl full-wave reduce
    float mx = sc[0][0];
#pragma unroll
    for (int nt = 0; nt < 4; ++nt)
#pragma unroll
      for (int r = 0; r < 4; ++r) mx = fmaxf(mx, sc[nt][r]);
    mx = fmaxf(mx, __shfl_xor(mx, 1, 64));
    mx = fmaxf(mx, __shfl_xor(mx, 2, 64));
    mx = fmaxf(mx, __shfl_xor(mx, 4, 64));
    mx = fmaxf(mx, __shfl_xor(mx, 8, 64));
    mx = fmaxf(mx, __shfl_xor(mx, 16, 64));
    mx = fmaxf(mx, __shfl_xor(mx, 32, 64));
    if (mx > mrow) {  // wave-uniform branch
      float al = __builtin_amdgcn_exp2f(mrow - mx);
      mrow = mx;
#pragma unroll
      for (int r = 0; r < 4; ++r) lsum[r] *= al;
#pragma unroll
      for (int dt = 0; dt < 4; ++dt)
#pragma unroll
        for (int r = 0; r < 4; ++r) oacc[dt][r] *= al;
    }
#pragma unroll
    for (int r = 0; r < 4; ++r) {
      float p0 = __builtin_amdgcn_exp2f(sc[0][r] - mrow);
      float p1 = __builtin_amdgcn_exp2f(sc[1][r] - mrow);
      float p2 = __builtin_amdgcn_exp2f(sc[2][r] - mrow);
      float p3 = __builtin_amdgcn_exp2f(sc[3][r] - mrow);
      lsum[r] += p0 + p1 + p2 + p3;
      Ps[w][quad * 4 + r][ln] = f2bf(p0);
      Ps[w][quad * 4 + r][16 + ln] = f2bf(p1);
      Ps[w][quad * 4 + r][32 + ln] = f2bf(p2);
      Ps[w][quad * 4 + r][48 + ln] = f2bf(p3);
    }

    // PV (P read back in A-operand layout; same-wave LDS program order)
    bf16x8_t pa0 = *(const bf16x8_t*)&Ps[w][ln][quad * 8];
    bf16x8_t pa1 = *(const bf16x8_t*)&Ps[w][ln][32 + quad * 8];
    __builtin_amdgcn_s_setprio(1);
#pragma unroll
    for (int dt = 0; dt < 4; ++dt) {
      bf16x8_t v0f = *(const bf16x8_t*)&Vt[dt * 16 + ln][quad * 8];
      oacc[dt] = __builtin_amdgcn_mfma_f32_16x16x32_bf16(pa0, v0f, oacc[dt], 0, 0, 0);
      bf16x8_t v1f = *(const bf16x8_t*)&Vt[dt * 16 + ln][32 + quad * 8];
      oacc[dt] = __builtin_amdgcn_mfma_f32_16x16x32_bf16(pa1, v1f, oacc[dt], 0, 0, 0);
    }
    __builtin_amdgcn_s_setprio(0);

    asm volatile("s_waitcnt lgkmcnt(0)\ns_barrier" ::: "memory");
    __builtin_amdgcn_sched_barrier(0);
    if (kt + 3 < 32) stage(cur);  // tile kt+3; flies ~2.5 iterations
    cur = (cur == 2) ? 0 : cur + 1;
  }

  // epilogue: reduce lane-partial sums once, normalize, store
  float inv[4];
#pragma unroll
  for (int r = 0; r < 4; ++r) {
    float t = lsum[r];
    t += __shfl_xor(t, 1, 64);
    t += __shfl_xor(t, 2, 64);
    t += __shfl_xor(t, 4, 64);
    t += __shfl_xor(t, 8, 64);
    inv[r] = 1.f / t;
  }
#pragma unroll
  for (int dt = 0; dt < 4; ++dt)
#pragma unroll
    for (int r = 0; r < 4; ++r) {
      int gm = b * SS + s0 + w * 16 + quad * 4 + r;
      Aob[(size_t)gm * DDIM + hh * 64 + dt * 16 + ln] = f2bf(oacc[dt][r] * inv[r]);
    }
}

// ---------------------------------------------------------------------------
// Launch
// ---------------------------------------------------------------------------
extern "C" void kernel_launch(void* const* d_in, const int* in_sizes, int n_in,
                              void* d_out, int out_size, void* d_ws, size_t ws_size,
                              hipStream_t stream) {
  const float* q    = (const float*)d_in[0];
  const float* k    = (const float*)d_in[1];
  const float* v    = (const float*)d_in[2];
  const float* wq_w = (const float*)d_in[3];
  const float* wq_b = (const float*)d_in[4];
  const float* wk_w = (const float*)d_in[5];
  const float* wk_b = (const float*)d_in[6];
  const float* wv_w = (const float*)d_in[7];
  const float* wv_b = (const float*)d_in[8];
  const float* wc_w = (const float*)d_in[9];
  const float* wc_b = (const float*)d_in[10];

  char* ws = (char*)d_ws;
  size_t off = 0;
  u16* zbuf = (u16*)(ws + off); off += 256;
  const size_t SZ_ACT = (size_t)2 * SS * DDIM * 2;  // 8 MB bf16
  u16* Xq  = (u16*)(ws + off); off += SZ_ACT;
  u16* Xk  = (u16*)(ws + off); off += SZ_ACT;
  u16* Xv  = (u16*)(ws + off); off += SZ_ACT;
  u16* Wqr = (u16*)(ws + off); off += (size_t)1024 * 3072 * 2;
  u16* Wkr = (u16*)(ws + off); off += (size_t)1024 * 3072 * 2;
  u16* Wvr = (u16*)(ws + off); off += (size_t)1024 * 1024 * 2;
  u16* Wcr = (u16*)(ws + off); off += (size_t)1024 * 1024 * 2;
  u16* Qhb = (u16*)(ws + off); off += SZ_ACT;
  u16* Khb = (u16*)(ws + off); off += SZ_ACT;
  u16* Vtb = (u16*)(ws + off); off += SZ_ACT;
  u16* Aob = (u16*)(ws + off); off += SZ_ACT;
  if (ws_size < off) return;

  prep_kernel<<<10240, 256, 0, stream>>>(q, k, v, wq_w, wk_w, wv_w, wc_w,
                                         Xq, Xk, Xv, Wqr, Wkr, Wvr, Wcr,
                                         (u32*)zbuf);

  // merged Q/K/V projections: depth-3 counted-vmcnt pipeline.
  // Q scale = 0.125 * log2(e): attention exps become exp2 (same rounding
  // error class: one bf16 round of Q either way).
  mfma_proj<<<dim3(32, 8, 3), 256, 0, stream>>>(
      Xq, Xk, Xv, Wqr, Wkr, Wvr, wq_b, wk_b, wv_b, Qhb, Khb, Vtb, zbuf,
      0.125f * 1.44269504f);

  mfma_attn<<<dim3(32, 32), 256, 0, stream>>>(Qhb, Khb, Vtb, Aob, zbuf);

  mfma_gemm_lin<<<dim3(128, 8), 256, 0, stream>>>(Aob, Wcr, wc_b, (float*)d_out);
}

// Round 11
// 364.604 us; speedup vs baseline: 1.0444x; 1.0401x over previous
//
#include <hip/hip_runtime.h>
#include <hip/hip_bf16.h>

#define SS 2048
#define DDIM 1024

typedef unsigned short u16;
typedef unsigned int u32;
typedef __attribute__((ext_vector_type(8))) short bf16x8_t;
typedef __attribute__((ext_vector_type(4))) float f32x4_t;

__device__ __forceinline__ u16 f2bf(float f) {
  __hip_bfloat16 h = __float2bfloat16(f);
  return *reinterpret_cast<u16*>(&h);
}

// async global->LDS, 16 B per lane. LDS dest = (wave-uniform) base + lane*16.
__device__ __forceinline__ void gld16(const void* g, void* lds_base) {
  __builtin_amdgcn_global_load_lds(
      (const __attribute__((address_space(1))) u32*)(uintptr_t)g,
      (__attribute__((address_space(3))) u32*)(u32)(uintptr_t)lds_base,
      16, 0, 0);
}

// ---------------------------------------------------------------------------
// Fused prep: zbuf zero + f32->bf16 converts + weight repacks. Grid 10240.
// ---------------------------------------------------------------------------
__global__ __launch_bounds__(256) void prep_kernel(
    const float* __restrict__ q, const float* __restrict__ k,
    const float* __restrict__ v, const float* __restrict__ wq_w,
    const float* __restrict__ wk_w, const float* __restrict__ wv_w,
    const float* __restrict__ wc_w, u16* __restrict__ Xq,
    u16* __restrict__ Xk, u16* __restrict__ Xv, u16* __restrict__ Wqr,
    u16* __restrict__ Wkr, u16* __restrict__ Wvr, u16* __restrict__ Wcr,
    u32* __restrict__ zbuf) {
  const int bid = blockIdx.x;
  const int tid = threadIdx.x;
  if (bid == 0 && tid < 64) zbuf[tid] = 0u;

  if (bid < 6144) {
    const int z = bid >> 11;            // 0..2
    const int bx = bid & 2047;
    const float* src = (z == 0) ? q : (z == 1) ? k : v;
    u16* dst = (z == 0) ? Xq : (z == 1) ? Xk : Xv;
    int i = bx * 256 + tid;
    const float4* s = (const float4*)src + (size_t)i * 2;
    float4 f0 = s[0], f1 = s[1];
    u16 o[8] = {f2bf(f0.x), f2bf(f0.y), f2bf(f0.z), f2bf(f0.w),
                f2bf(f1.x), f2bf(f1.y), f2bf(f1.z), f2bf(f1.w)};
    *(uint4*)(dst + (size_t)i * 8) = *(const uint4*)o;
  } else if (bid < 8192) {
    const int idx = bid - 6144;
    const float* w = (idx >= 1024) ? wk_w : wq_w;
    u16* out = (idx >= 1024) ? Wkr : Wqr;
    const int o = idx & 1023;
    for (int j = tid; j < 3072; j += 256) {
      int i = j / 3, t = j - i * 3;
      out[(size_t)o * 3072 + t * 1024 + i] = f2bf(w[(size_t)o * 3072 + j]);
    }
  } else {
    const int idx = bid - 8192;
    const float* w = (idx >= 1024) ? wc_w : wv_w;
    u16* out = (idx >= 1024) ? Wcr : Wvr;
    const int bx = idx & 1023;
    size_t i = (size_t)bx * 1024 + tid * 4;
    float4 f = *(const float4*)(w + i);
    u16 o4[4] = {f2bf(f.x), f2bf(f.y), f2bf(f.z), f2bf(f.w)};
    *(ushort4*)(out + i) = *(const ushort4*)o4;
  }
}

// ---------------------------------------------------------------------------
// Merged Q/K/V projection GEMM (r8-exact config: best measured, 128.8 us).
// grid (32, 8, 3). 128x128 tile, BK=32, depth-2 counted-vmcnt pipeline,
// 40 KB LDS (3 blocks/CU). r9 (bigger tile) and r10 (depth-3) both
// regressed: the 2-phase structure is saturated at this shape.
// ---------------------------------------------------------------------------
__global__ __launch_bounds__(256) void mfma_proj(
    const u16* __restrict__ Xq, const u16* __restrict__ Xk,
    const u16* __restrict__ Xv, const u16* __restrict__ Wq,
    const u16* __restrict__ Wk, const u16* __restrict__ Wv,
    const float* __restrict__ bq, const float* __restrict__ bk,
    const float* __restrict__ bv, u16* __restrict__ Qhb,
    u16* __restrict__ Khb, u16* __restrict__ Vtb,
    const u16* __restrict__ zbuf, float qscale) {
  __shared__ __attribute__((aligned(16))) u16 As2[2][128][40];
  __shared__ __attribute__((aligned(16))) u16 Bs2[2][128][40];
  const int z = blockIdx.z;
  const u16* __restrict__ Xb = (z == 0) ? Xq : (z == 1) ? Xk : Xv;
  const u16* __restrict__ Wr = (z == 0) ? Wq : (z == 1) ? Wk : Wv;
  const float* __restrict__ bias = (z == 0) ? bq : (z == 1) ? bk : bv;
  u16* __restrict__ Cptr = (z == 0) ? Qhb : (z == 1) ? Khb : Vtb;
  const int nk = (z == 2) ? 32 : 96;
  const bool conv = (z < 2);
  const bool vout = (z == 2);
  const float scale = (z == 0) ? qscale : 1.0f;
  const int Kdim = (z == 2) ? 1024 : 3072;

  const int tid = threadIdx.x;
  const int lane = tid & 63;
  const int w = tid >> 6;
  const int ln = tid & 15;
  const int quad = (tid >> 4) & 3;
  const int wrow = w >> 1, wcol = w & 1;
  const int m0 = blockIdx.x * 128, n0 = blockIdx.y * 128;

  // ---- hoisted per-slot staging state (slot i: c = w + 4i) ----
  const char* p[5];
  int dinc[5];
  u32 ldso[5];
  bool act[5], isA[5], loA[5], hiA[5];
  const char* pbaseA[5];

#pragma unroll
  for (int i = 0; i < 5; ++i) {
    int c = w + 4 * i;
    isA[i] = (c < 10);
    loA[i] = hiA[i] = false;
    pbaseA[i] = nullptr;
    if (c < 10) {
      int G = c * 64 + lane;
      int x = G / 5, kb = G - x * 5;
      int gm = m0 + x;
      int b = gm >> 11, s = gm & 2047;
      act[i] = (kb < 4);
      ldso[i] = c * 1024;
      const char* pb = (const char*)(Xb + (size_t)(b * SS + s) * DDIM + kb * 8);
      pbaseA[i] = pb;
      loA[i] = (s == 0);
      hiA[i] = (s == 2047);
      if (conv) {
        p[i] = loA[i] ? (const char*)zbuf : (pb - 2048);  // t=0: row s-1
        dinc[i] = loA[i] ? 0 : 64;
      } else {
        p[i] = pb;
        dinc[i] = 64;
      }
    } else {
      int c2 = c - 10;
      int G = c2 * 64 + lane;
      int x = G / 5, kb = G - x * 5;
      act[i] = (kb < 4);
      ldso[i] = c2 * 1024;
      p[i] = (const char*)(Wr + (size_t)(n0 + x) * Kdim + kb * 8);
      dinc[i] = 64;
    }
  }

  // each call issues EXACTLY 5 gld16 per wave (vmcnt accounting relies on it)
  auto stage = [&](int bi) {
#pragma unroll
    for (int i = 0; i < 5; ++i) {
      char* dst = (isA[i] ? (char*)As2[bi] : (char*)Bs2[bi]) + ldso[i];
      if (act[i]) gld16(p[i], dst);
      p[i] += dinc[i];
    }
  };

  f32x4_t acc[4][4];
#pragma unroll
  for (int i = 0; i < 4; ++i)
#pragma unroll
    for (int j = 0; j < 4; ++j) acc[i][j] = (f32x4_t){0.f, 0.f, 0.f, 0.f};

  stage(0);  // tile 0 -> buf 0
  stage(1);  // tile 1 -> buf 1 (10 outstanding/wave)

#pragma unroll 2
  for (int ks = 0; ks < nk; ++ks) {
    const int cur = ks & 1;
    if (ks + 1 < nk)
      asm volatile("s_waitcnt vmcnt(5)\ns_barrier" ::: "memory");
    else
      asm volatile("s_waitcnt vmcnt(0)\ns_barrier" ::: "memory");

    const u16(*As)[40] = As2[cur];
    const u16(*Bs)[40] = Bs2[cur];
    bf16x8_t a[4], b[4];
#pragma unroll
    for (int mt = 0; mt < 4; ++mt)
      a[mt] = *(const bf16x8_t*)&As[wrow * 64 + mt * 16 + ln][quad * 8];
#pragma unroll
    for (int nt = 0; nt < 4; ++nt)
      b[nt] = *(const bf16x8_t*)&Bs[wcol * 64 + nt * 16 + ln][quad * 8];
    // MFMAs directly after reads: compiler emits fine-grained lgkmcnt
    __builtin_amdgcn_s_setprio(1);
#pragma unroll
    for (int mt = 0; mt < 4; ++mt)
#pragma unroll
      for (int nt = 0; nt < 4; ++nt)
        acc[mt][nt] = __builtin_amdgcn_mfma_f32_16x16x32_bf16(
            a[mt], b[nt], acc[mt][nt], 0, 0, 0);
    __builtin_amdgcn_s_setprio(0);

    asm volatile("s_waitcnt lgkmcnt(0)\ns_barrier" ::: "memory");
    __builtin_amdgcn_sched_barrier(0);  // keep reads/MFMA above this point

    const int j = ks + 2;
    if (j < nk) {
      if (conv && (j & 31) == 0) {  // staged tile crosses a t-phase boundary
#pragma unroll
        for (int i = 0; i < 5; ++i) {
          if (isA[i]) {
            if (j == 32) {  // entering t=1: unfreeze s==0 rows
              if (loA[i]) { p[i] = pbaseA[i]; dinc[i] = 64; }
            } else {        // entering t=2: freeze s==2047 rows
              if (hiA[i]) { p[i] = (const char*)zbuf; dinc[i] = 0; }
            }
          }
        }
      }
      stage(cur);  // tile ks+2 -> just-freed buffer; flies over iter ks+1
    }
  }

#pragma unroll
  for (int mt = 0; mt < 4; ++mt) {
#pragma unroll
    for (int nt = 0; nt < 4; ++nt) {
      int gn = n0 + wcol * 64 + nt * 16 + ln;
      float bi = bias[gn];
#pragma unroll
      for (int r = 0; r < 4; ++r) {
        int gm = m0 + wrow * 64 + mt * 16 + quad * 4 + r;
        float val = (acc[mt][nt][r] + bi) * scale;
        int b = gm >> 11, s = gm & 2047;
        int hh = gn & 15, dd = gn >> 4;  // channel = dd*16 + hh (head FAST)
        if (!vout)
          Cptr[((size_t)(b * 16 + hh) * SS + s) * 64 + dd] = f2bf(val);
        else
          Cptr[((size_t)(b * 16 + hh) * 64 + dd) * SS + s] = f2bf(val);
      }
    }
  }
}

// ---------------------------------------------------------------------------
// Final linear GEMM (r8-exact). 32x128 tile, grid (128, 8), depth-2.
// ---------------------------------------------------------------------------
__global__ __launch_bounds__(256) void mfma_gemm_lin(
    const u16* __restrict__ Xb, const u16* __restrict__ Wr,
    const float* __restrict__ bias, float* __restrict__ Cptr) {
  __shared__ __attribute__((aligned(16))) u16 As2[2][32][40];
  __shared__ __attribute__((aligned(16))) u16 Bs2[2][128][40];
  const int tid = threadIdx.x;
  const int lane = tid & 63;
  const int w = tid >> 6;
  const int ln = tid & 15;
  const int quad = (tid >> 4) & 3;
  const int wrow = w >> 1, wcol = w & 1;
  const int m0 = blockIdx.x * 32, n0 = blockIdx.y * 128;

  const char* p[4];
  u32 ldso[4];
  bool ok[4], act[4], isA[4];
#pragma unroll
  for (int i = 0; i < 4; ++i) {
    int c = w + 4 * i;
    ok[i] = (c < 13);
    if (c < 3) {
      int G = c * 64 + lane;
      int x = G / 5, kb = G - x * 5;
      isA[i] = true;
      act[i] = (kb < 4) && (x < 32);
      ldso[i] = c * 1024;
      p[i] = (const char*)(Xb + (size_t)(m0 + x) * DDIM + kb * 8);
    } else if (c < 13) {
      int c2 = c - 3;
      int G = c2 * 64 + lane;
      int x = G / 5, kb = G - x * 5;
      isA[i] = false;
      act[i] = (kb < 4);
      ldso[i] = c2 * 1024;
      p[i] = (const char*)(Wr + (size_t)(n0 + x) * 1024 + kb * 8);
    } else {
      isA[i] = false; act[i] = false; ldso[i] = 0; p[i] = nullptr;
    }
  }

  auto stage = [&](int bi) {
#pragma unroll
    for (int i = 0; i < 4; ++i) {
      if (ok[i]) {
        char* dst = (isA[i] ? (char*)As2[bi] : (char*)Bs2[bi]) + ldso[i];
        if (act[i]) gld16(p[i], dst);
        p[i] += 64;
      }
    }
  };

  f32x4_t acc[4];
#pragma unroll
  for (int j = 0; j < 4; ++j) acc[j] = (f32x4_t){0.f, 0.f, 0.f, 0.f};

  stage(0);
  stage(1);

#pragma unroll 2
  for (int ks = 0; ks < 32; ++ks) {
    const int cur = ks & 1;
    if (ks + 1 < 32) {
      if (w == 0) asm volatile("s_waitcnt vmcnt(4)\ns_barrier" ::: "memory");
      else        asm volatile("s_waitcnt vmcnt(3)\ns_barrier" ::: "memory");
    } else {
      asm volatile("s_waitcnt vmcnt(0)\ns_barrier" ::: "memory");
    }

    const u16(*As)[40] = As2[cur];
    const u16(*Bs)[40] = Bs2[cur];
    bf16x8_t a = *(const bf16x8_t*)&As[wrow * 16 + ln][quad * 8];
    bf16x8_t b[4];
#pragma unroll
    for (int nt = 0; nt < 4; ++nt)
      b[nt] = *(const bf16x8_t*)&Bs[wcol * 64 + nt * 16 + ln][quad * 8];
    __builtin_amdgcn_s_setprio(1);
#pragma unroll
    for (int nt = 0; nt < 4; ++nt)
      acc[nt] = __builtin_amdgcn_mfma_f32_16x16x32_bf16(a, b[nt], acc[nt], 0, 0, 0);
    __builtin_amdgcn_s_setprio(0);

    asm volatile("s_waitcnt lgkmcnt(0)\ns_barrier" ::: "memory");
    __builtin_amdgcn_sched_barrier(0);

    if (ks + 2 < 32) stage(cur);
  }

#pragma unroll
  for (int nt = 0; nt < 4; ++nt) {
    int gn = n0 + wcol * 64 + nt * 16 + ln;
    float bi = bias[gn];
#pragma unroll
    for (int r = 0; r < 4; ++r) {
      int gm = m0 + wrow * 16 + quad * 4 + r;
      Cptr[(size_t)gm * DDIM + gn] = acc[nt][r] + bi;
    }
  }
}

// ---------------------------------------------------------------------------
// MFMA flash attention (r8 structure: depth-2, 46 KB LDS, wave-shared max)
// + exp2 softmax (Q pre-scaled by 0.125*log2e)
// + NEW: XCD-aware block swizzle (T1). The 32 blocks sharing one head's
//   K/V (512 KB) previously round-robined across all 8 XCDs -> each XCD's
//   L2 re-fetched K/V from HBM (attn FETCH 69.7 MB vs ~24 ideal) and
//   staging loads were ~900cyc HBM misses. Remap so all blocks of head bh
//   share XCD residue bh%8: each XCD serves 4 heads x 512 KB = 2 MB of K/V
//   (fits 4 MB L2); staging becomes L2-resident and the 2-deep pipeline
//   covers it. lin = x + y*32; bh = (lin>>8)*8 + (lin&7); s0idx=(lin>>3)&31.
// ---------------------------------------------------------------------------
__global__ __launch_bounds__(256) void mfma_attn(
    const u16* __restrict__ Qhb, const u16* __restrict__ Khb,
    const u16* __restrict__ Vtb, u16* __restrict__ Aob,
    const u16* __restrict__ zbuf) {
  __shared__ __attribute__((aligned(16))) u16 Ks2[2][64][72];
  __shared__ __attribute__((aligned(16))) u16 Vt2[2][64][72];
  __shared__ __attribute__((aligned(16))) u16 Ps[4][16][72];
  const int tid = threadIdx.x;
  const int lane = tid & 63;
  const int w = tid >> 6;
  const int ln = tid & 15;
  const int quad = (tid >> 4) & 3;
  // XCD swizzle: all s0-tiles of a head land on one XCD residue (bh%8)
  const int lin = blockIdx.x + blockIdx.y * 32;
  const int bh = ((lin >> 8) << 3) | (lin & 7);
  const int b = bh >> 4, hh = bh & 15;
  const int s0 = ((lin >> 3) & 31) * 64;

  const char* p[5];
  int dinc[5];
  u32 ldso[5];
  bool ok[5], act[5], isK[5];
#pragma unroll
  for (int i = 0; i < 5; ++i) {
    int c = w + 4 * i;
    ok[i] = (c < 18);
    if (c < 9) {
      int G = c * 64 + lane;
      int x = G / 9, db = G - x * 9;
      isK[i] = true;
      act[i] = (db < 8);
      ldso[i] = c * 1024;
      p[i] = (const char*)(Khb + ((size_t)bh * SS + x) * 64 + db * 8);
      dinc[i] = 8192;
    } else if (c < 18) {
      int c2 = c - 9;
      int G = c2 * 64 + lane;
      int x = G / 9, db = G - x * 9;
      isK[i] = false;
      act[i] = (db < 8);
      ldso[i] = c2 * 1024;
      p[i] = (const char*)(Vtb + ((size_t)bh * 64 + x) * SS + db * 8);
      dinc[i] = 128;
    } else {
      isK[i] = false; ok[i] = false; act[i] = false; ldso[i] = 0;
      p[i] = nullptr; dinc[i] = 0;
    }
  }

  auto stage = [&](int bi) {
#pragma unroll
    for (int i = 0; i < 5; ++i) {
      if (ok[i]) {
        char* dst = (isK[i] ? (char*)Ks2[bi] : (char*)Vt2[bi]) + ldso[i];
        if (act[i]) gld16(p[i], dst);
        p[i] += dinc[i];
      }
    }
  };

  const u16* qp = Qhb + ((size_t)bh * SS + s0 + w * 16 + ln) * 64 + quad * 8;
  bf16x8_t qf0 = *(const bf16x8_t*)qp;
  bf16x8_t qf1 = *(const bf16x8_t*)(qp + 32);

  float mrow = -3e38f;  // wave-shared running max (log2 domain)
  float lsum[4];
  f32x4_t oacc[4];
#pragma unroll
  for (int r = 0; r < 4; ++r) lsum[r] = 0.f;
#pragma unroll
  for (int dt = 0; dt < 4; ++dt) oacc[dt] = (f32x4_t){0.f, 0.f, 0.f, 0.f};

  stage(0);
  stage(1);

#pragma unroll 2
  for (int kt = 0; kt < 32; ++kt) {
    const int cur = kt & 1;
    if (kt + 1 < 32) {
      if (w < 2) asm volatile("s_waitcnt vmcnt(5)\ns_barrier" ::: "memory");
      else       asm volatile("s_waitcnt vmcnt(4)\ns_barrier" ::: "memory");
    } else {
      asm volatile("s_waitcnt vmcnt(0)\ns_barrier" ::: "memory");
    }

    const u16(*Ks)[72] = Ks2[cur];
    const u16(*Vt)[72] = Vt2[cur];

    f32x4_t sc[4];
#pragma unroll
    for (int nt = 0; nt < 4; ++nt) sc[nt] = (f32x4_t){0.f, 0.f, 0.f, 0.f};
    __builtin_amdgcn_s_setprio(1);
#pragma unroll
    for (int nt = 0; nt < 4; ++nt) {
      bf16x8_t k0f = *(const bf16x8_t*)&Ks[nt * 16 + ln][quad * 8];
      sc[nt] = __builtin_amdgcn_mfma_f32_16x16x32_bf16(qf0, k0f, sc[nt], 0, 0, 0);
      bf16x8_t k1f = *(const bf16x8_t*)&Ks[nt * 16 + ln][32 + quad * 8];
      sc[nt] = __builtin_amdgcn_mfma_f32_16x16x32_bf16(qf1, k1f, sc[nt], 0, 0, 0);
    }
    __builtin_amdgcn_s_setprio(0);

    // wave-shared max: local max over 16 regs, then 6-shfl full-wave reduce
    float mx = sc[0][0];
#pragma unroll
    for (int nt = 0; nt < 4; ++nt)
#pragma unroll
      for (int r = 0; r < 4; ++r) mx = fmaxf(mx, sc[nt][r]);
    mx = fmaxf(mx, __shfl_xor(mx, 1, 64));
    mx = fmaxf(mx, __shfl_xor(mx, 2, 64));
    mx = fmaxf(mx, __shfl_xor(mx, 4, 64));
    mx = fmaxf(mx, __shfl_xor(mx, 8, 64));
    mx = fmaxf(mx, __shfl_xor(mx, 16, 64));
    mx = fmaxf(mx, __shfl_xor(mx, 32, 64));
    if (mx > mrow) {  // wave-uniform branch
      float al = __builtin_amdgcn_exp2f(mrow - mx);
      mrow = mx;
#pragma unroll
      for (int r = 0; r < 4; ++r) lsum[r] *= al;
#pragma unroll
      for (int dt = 0; dt < 4; ++dt)
#pragma unroll
        for (int r = 0; r < 4; ++r) oacc[dt][r] *= al;
    }
#pragma unroll
    for (int r = 0; r < 4; ++r) {
      float p0 = __builtin_amdgcn_exp2f(sc[0][r] - mrow);
      float p1 = __builtin_amdgcn_exp2f(sc[1][r] - mrow);
      float p2 = __builtin_amdgcn_exp2f(sc[2][r] - mrow);
      float p3 = __builtin_amdgcn_exp2f(sc[3][r] - mrow);
      lsum[r] += p0 + p1 + p2 + p3;
      Ps[w][quad * 4 + r][ln] = f2bf(p0);
      Ps[w][quad * 4 + r][16 + ln] = f2bf(p1);
      Ps[w][quad * 4 + r][32 + ln] = f2bf(p2);
      Ps[w][quad * 4 + r][48 + ln] = f2bf(p3);
    }

    // PV (P read back in A-operand layout; same-wave LDS program order)
    bf16x8_t pa0 = *(const bf16x8_t*)&Ps[w][ln][quad * 8];
    bf16x8_t pa1 = *(const bf16x8_t*)&Ps[w][ln][32 + quad * 8];
    __builtin_amdgcn_s_setprio(1);
#pragma unroll
    for (int dt = 0; dt < 4; ++dt) {
      bf16x8_t v0f = *(const bf16x8_t*)&Vt[dt * 16 + ln][quad * 8];
      oacc[dt] = __builtin_amdgcn_mfma_f32_16x16x32_bf16(pa0, v0f, oacc[dt], 0, 0, 0);
      bf16x8_t v1f = *(const bf16x8_t*)&Vt[dt * 16 + ln][32 + quad * 8];
      oacc[dt] = __builtin_amdgcn_mfma_f32_16x16x32_bf16(pa1, v1f, oacc[dt], 0, 0, 0);
    }
    __builtin_amdgcn_s_setprio(0);

    asm volatile("s_waitcnt lgkmcnt(0)\ns_barrier" ::: "memory");
    __builtin_amdgcn_sched_barrier(0);
    if (kt + 2 < 32) stage(cur);  // tile kt+2; flies over all of iter kt+1
  }

  // epilogue: reduce lane-partial sums once, normalize, store
  float inv[4];
#pragma unroll
  for (int r = 0; r < 4; ++r) {
    float t = lsum[r];
    t += __shfl_xor(t, 1, 64);
    t += __shfl_xor(t, 2, 64);
    t += __shfl_xor(t, 4, 64);
    t += __shfl_xor(t, 8, 64);
    inv[r] = 1.f / t;
  }
#pragma unroll
  for (int dt = 0; dt < 4; ++dt)
#pragma unroll
    for (int r = 0; r < 4; ++r) {
      int gm = b * SS + s0 + w * 16 + quad * 4 + r;
      Aob[(size_t)gm * DDIM + hh * 64 + dt * 16 + ln] = f2bf(oacc[dt][r] * inv[r]);
    }
}

// ---------------------------------------------------------------------------
// Launch
// ---------------------------------------------------------------------------
extern "C" void kernel_launch(void* const* d_in, const int* in_sizes, int n_in,
                              void* d_out, int out_size, void* d_ws, size_t ws_size,
                              hipStream_t stream) {
  const float* q    = (const float*)d_in[0];
  const float* k    = (const float*)d_in[1];
  const float* v    = (const float*)d_in[2];
  const float* wq_w = (const float*)d_in[3];
  const float* wq_b = (const float*)d_in[4];
  const float* wk_w = (const float*)d_in[5];
  const float* wk_b = (const float*)d_in[6];
  const float* wv_w = (const float*)d_in[7];
  const float* wv_b = (const float*)d_in[8];
  const float* wc_w = (const float*)d_in[9];
  const float* wc_b = (const float*)d_in[10];

  char* ws = (char*)d_ws;
  size_t off = 0;
  u16* zbuf = (u16*)(ws + off); off += 256;
  const size_t SZ_ACT = (size_t)2 * SS * DDIM * 2;  // 8 MB bf16
  u16* Xq  = (u16*)(ws + off); off += SZ_ACT;
  u16* Xk  = (u16*)(ws + off); off += SZ_ACT;
  u16* Xv  = (u16*)(ws + off); off += SZ_ACT;
  u16* Wqr = (u16*)(ws + off); off += (size_t)1024 * 3072 * 2;
  u16* Wkr = (u16*)(ws + off); off += (size_t)1024 * 3072 * 2;
  u16* Wvr = (u16*)(ws + off); off += (size_t)1024 * 1024 * 2;
  u16* Wcr = (u16*)(ws + off); off += (size_t)1024 * 1024 * 2;
  u16* Qhb = (u16*)(ws + off); off += SZ_ACT;
  u16* Khb = (u16*)(ws + off); off += SZ_ACT;
  u16* Vtb = (u16*)(ws + off); off += SZ_ACT;
  u16* Aob = (u16*)(ws + off); off += SZ_ACT;
  if (ws_size < off) return;

  prep_kernel<<<10240, 256, 0, stream>>>(q, k, v, wq_w, wk_w, wv_w, wc_w,
                                         Xq, Xk, Xv, Wqr, Wkr, Wvr, Wcr,
                                         (u32*)zbuf);

  // merged Q/K/V projections (r8 config). Q scale = 0.125*log2(e): attention
  // exps become exp2 (same rounding class: one bf16 round of Q either way).
  mfma_proj<<<dim3(32, 8, 3), 256, 0, stream>>>(
      Xq, Xk, Xv, Wqr, Wkr, Wvr, wq_b, wk_b, wv_b, Qhb, Khb, Vtb, zbuf,
      0.125f * 1.44269504f);

  mfma_attn<<<dim3(32, 32), 256, 0, stream>>>(Qhb, Khb, Vtb, Aob, zbuf);

  mfma_gemm_lin<<<dim3(128, 8), 256, 0, stream>>>(Aob, Wcr, wc_b, (float*)d_out);
}